// Round 4
// baseline (208.876 us; speedup 1.0000x reference)
//
#include <hip/hip_runtime.h>
#include <math.h>

// (B,S,D,C) = (64, 576, 768, 200)
#define Bsz  64
#define Ssz  576
#define Dsz  768
#define Csz  200
#define NPAD 208        // 13 tiles of 16: 0..199 classes, row 200 = ones (rowsum), 201..207 zero
#define MT   48         // rows per block; grid 768
#define BK   64
#define NKT  12

typedef float f32x4 __attribute__((ext_vector_type(4)));

#define AS_GLOBAL __attribute__((address_space(1)))
#define AS_LDS    __attribute__((address_space(3)))

// async 16B-per-lane global -> LDS (dest = wave-uniform base + lane*16)
__device__ inline void gload16(const void* g, void* l) {
    __builtin_amdgcn_global_load_lds((const AS_GLOBAL unsigned int*)g,
                                     (AS_LDS unsigned int*)l, 16, 0, 0);
}

// one-time: W (200x768 fp32) -> fp8 e4m3 (208x768); row 200 = 1.0 (rowsum), 201..207 = 0
__global__ __launch_bounds__(256) void prep_w8(const float* __restrict__ W,
                                               unsigned int* __restrict__ Wq) {
    const int i   = blockIdx.x * 256 + threadIdx.x;   // u32 index over NPAD*768/4 = 39936
    const int row = i / 192;
    const int col = (i % 192) * 4;
    unsigned int w = 0;
    if (row < Csz) {
        const float4 v = *(const float4*)(W + (size_t)row * Dsz + col);
        w = __builtin_amdgcn_cvt_pk_fp8_f32(v.x, v.y, 0u, false);
        w = __builtin_amdgcn_cvt_pk_fp8_f32(v.z, v.w, w, true);
    } else if (row == Csz) {
        w = 0x38383838u;   // fp8 e4m3 1.0 x4
    }
    Wq[i] = w;
}

// global classifier runs FIRST: out[b,c] = ct[b]·gw[c] + gb[c]  (exact fp32)
__global__ __launch_bounds__(256) void gc_kernel(
    const float* __restrict__ ct, const float* __restrict__ gw,
    const float* __restrict__ gb, float* __restrict__ out) {
    const int b    = blockIdx.x;
    const int wv   = threadIdx.x >> 6;
    const int lane = threadIdx.x & 63;
    const int c    = blockIdx.y * 4 + wv;
    const float* wr = gw + (size_t)c * Dsz + lane * 12;
    const float* cr = ct + (size_t)b * Dsz + lane * 12;
    float s = 0.f;
#pragma unroll
    for (int j = 0; j < 3; ++j) {
        const float4 w = *(const float4*)(wr + 4 * j);
        const float4 x = *(const float4*)(cr + 4 * j);
        s += w.x * x.x + w.y * x.y + w.z * x.z + w.w * x.w;
    }
#pragma unroll
    for (int off = 32; off > 0; off >>= 1) s += __shfl_down(s, off, 64);
    if (lane == 0) out[b * Csz + c] = s + gb[c];
}

// R0 structure + T4 counted-vmcnt: triple-buffered DMA, raw s_barrier with
// per-wave counted s_waitcnt (never vmcnt(0) in the main loop). Each batch is
// in flight for TWO consume phases before its wait. 75 KB LDS -> 2 blocks/CU.
// Waves 0-2: consumers (one 16-row tile x 13 class tiles) + 6 DMA/iter.
// Wave 3: DMA-only (4/iter).
__global__ __launch_bounds__(256, 2) void attn_kernel(
    const float* __restrict__ X,            // (B*S, D) fp32
    const unsigned char* __restrict__ Wq,   // (NPAD, D) fp8 e4m3
    const float* __restrict__ attn_b,       // (C,)
    const float* __restrict__ lam,          // (1,)
    float* __restrict__ out)                // (B, C): gscore already written
{
    __shared__ float         sX[3][MT * BK];      // 3 x 12 KB (768 chunks: row=s>>4, cp=s&15)
    __shared__ unsigned char sW[3][NPAD * BK];    // 3 x 13 KB (832 chunks: row=s>>2, cp=s&3)

    const int tid  = threadIdx.x;
    const int lane = tid & 63;
    const int w    = tid >> 6;
    const int m    = lane & 15;
    const int q    = lane >> 4;
    const int rowbase = blockIdx.x * MT;
    const int bidx    = blockIdx.x / 12;          // 12 blocks per batch, never crosses

    // ---- X DMA: 768 chunks = 12 groups of 64; wave w issues groups 3w..3w+2.
    // slot s=(g*64+lane): row = s>>4 = g*4 + (lane>>4), holds global chunk (lane&15)^(row&15).
    const float* xg[3];
    int xsl[3];
#pragma unroll
    for (int j = 0; j < 3; ++j) {
        const int g    = 3 * w + j;
        const int xrow = g * 4 + (lane >> 4);
        const int xgc  = (lane & 15) ^ (xrow & 15);
        xg[j]  = X + (size_t)(rowbase + xrow) * Dsz + xgc * 4;
        xsl[j] = g * 64;                           // dest chunk base (lane*16 implicit)
    }

    // ---- W DMA: 832 chunks = 13 groups; waves take groups {3w..}, wave 3 gets 4.
    // slot s: row = g*16 + (lane>>2), holds global chunk (lane&3)^((lane>>2)&3).
    const int wng = (w < 3) ? 3 : 4;
    const int wg0 = 3 * w;
    const unsigned char* wgp = Wq + (size_t)(lane >> 2) * Dsz
                                  + (((lane & 3) ^ ((lane >> 2) & 3)) * 16);

    f32x4 acc[13];
#pragma unroll
    for (int t = 0; t < 13; ++t) acc[t] = (f32x4){0.f, 0.f, 0.f, 0.f};

    // ---- consumer offsets (waves 0-2): A row rA = w*16+m, key rA&15
    const int rA   = w * 16 + m;
    const int akey = rA & 15;
    const int bkey = m & 3;

    // ---- prologue: batch 0 -> buf 0, batch 1 -> buf 1
#pragma unroll
    for (int kt = 0; kt < 2; ++kt) {
#pragma unroll
        for (int j = 0; j < 3; ++j)
            gload16(xg[j] + kt * BK, &sX[kt][xsl[j] * 4]);
#pragma unroll
        for (int j = 0; j < 4; ++j)
            if (j < wng) gload16(wgp + (size_t)(wg0 + j) * 16 * Dsz + kt * BK,
                                 &sW[kt][(wg0 + j) * 1024]);
    }

#pragma unroll
    for (int kt = 0; kt < NKT; ++kt) {
        const int p = kt % 3;
        // counted wait: batch kt (issued 2 iters ago) must be done; batch kt+1
        // stays in flight across the barrier. Never vmcnt(0) mid-loop (T4).
        if (kt == NKT - 1) {
            asm volatile("s_waitcnt vmcnt(0)\n\ts_barrier" ::: "memory");
        } else if (w < 3) {
            asm volatile("s_waitcnt vmcnt(6)\n\ts_barrier" ::: "memory");
        } else {
            asm volatile("s_waitcnt vmcnt(4)\n\ts_barrier" ::: "memory");
        }
        // issue batch kt+2 into buf (kt+2)%3 = (kt-1)%3: its consumers all
        // passed the barrier above, so the buffer is free (no lap race).
        if (kt + 2 < NKT) {
            const int pn = (kt + 2) % 3;
            const int kx = (kt + 2) * BK;          // floats for X, bytes for W
#pragma unroll
            for (int j = 0; j < 3; ++j)
                gload16(xg[j] + kx, &sX[pn][xsl[j] * 4]);
#pragma unroll
            for (int j = 0; j < 4; ++j)
                if (j < wng) gload16(wgp + (size_t)(wg0 + j) * 16 * Dsz + kx,
                                     &sW[pn][(wg0 + j) * 1024]);
        }
        if (w < 3) {
            __builtin_amdgcn_s_setprio(1);
#pragma unroll
            for (int k2 = 0; k2 < 2; ++k2) {
                const int c0 = k2 * 8 + 2 * q;
                const float4 alo = *(const float4*)&sX[p][rA * 64 + ((c0) ^ akey) * 4];
                const float4 ahi = *(const float4*)&sX[p][rA * 64 + ((c0 + 1) ^ akey) * 4];
                union { long l; unsigned int u[2]; } A;
                A.u[0] = __builtin_amdgcn_cvt_pk_fp8_f32(alo.x, alo.y, 0u, false);
                A.u[0] = __builtin_amdgcn_cvt_pk_fp8_f32(alo.z, alo.w, A.u[0], true);
                A.u[1] = __builtin_amdgcn_cvt_pk_fp8_f32(ahi.x, ahi.y, 0u, false);
                A.u[1] = __builtin_amdgcn_cvt_pk_fp8_f32(ahi.z, ahi.w, A.u[1], true);
                const unsigned char* wb =
                    &sW[p][m * 64 + ((k2 * 2 + (q >> 1)) ^ bkey) * 16 + (q & 1) * 8];
#pragma unroll
                for (int t = 0; t < 13; ++t) {
                    const long B = *(const long*)(wb + t * 1024);
                    acc[t] = __builtin_amdgcn_mfma_f32_16x16x32_fp8_fp8(A.l, B, acc[t], 0, 0, 0);
                }
            }
            __builtin_amdgcn_s_setprio(0);
        }
    }

    if (w < 3) {
        // rowsum via ones-column: tile 12, col 200 => m==8 lanes; row = q*4+r
        float rsv[4];
#pragma unroll
        for (int r = 0; r < 4; ++r) rsv[r] = __shfl(acc[12][r], (lane & 48) + 8, 64);

        const float scale = lam[0] * (1.f / ((float)Ssz * (float)Dsz));
        // epilogue: C/D col = lane&15, row = q*4+reg; reduce tile's 16 rows, atomic add
#pragma unroll
        for (int t = 0; t < 13; ++t) {
            const int c = t * 16 + m;
            if (c < Csz) {
                const float bias = attn_b[c];
                float s = 0.f;
#pragma unroll
                for (int r = 0; r < 4; ++r)
                    s += rsv[r] / (1.f + __expf(-(acc[t][r] + bias)));
                s += __shfl_xor(s, 16, 64);
                s += __shfl_xor(s, 32, 64);
                if (q == 0) atomicAdd(&out[bidx * Csz + c], s * scale);
            }
        }
    }
}

extern "C" void kernel_launch(void* const* d_in, const int* in_sizes, int n_in,
                              void* d_out, int out_size, void* d_ws, size_t ws_size,
                              hipStream_t stream) {
    const float* X   = (const float*)d_in[0];
    const float* ct  = (const float*)d_in[1];
    const float* aw  = (const float*)d_in[2];
    const float* ab  = (const float*)d_in[3];
    const float* gw  = (const float*)d_in[4];
    const float* gb  = (const float*)d_in[5];
    const float* lam = (const float*)d_in[6];
    float* out = (float*)d_out;
    unsigned char* Wq = (unsigned char*)d_ws;   // 208*768 = 156 KB fp8

    prep_w8<<<(NPAD * Dsz / 4) / 256, 256, 0, stream>>>(aw, (unsigned int*)Wq);
    gc_kernel<<<dim3(Bsz, Csz / 4), 256, 0, stream>>>(ct, gw, gb, out);
    attn_kernel<<<(Bsz * Ssz) / MT, 256, 0, stream>>>(X, Wq, ab, lam, out);
}

// Round 5
// 196.980 us; speedup vs baseline: 1.0604x; 1.0604x over previous
//
#include <hip/hip_runtime.h>
#include <math.h>

// (B,S,D,C) = (64, 576, 768, 200)
#define Bsz  64
#define Ssz  576
#define Dsz  768
#define Csz  200
#define NKT  12         // K tiles of 64 floats (3 per wave)

typedef float f32x4 __attribute__((ext_vector_type(4)));
typedef long  lx2   __attribute__((ext_vector_type(2)));

// one-time: W (200x768 fp32) -> fp8 e4m3 pre-swizzled into MFMA B-fragment order.
// Record (kt,t) = 1024 B at ((kt*13+t)*1024): lane l holds 16 B = [k2=0 8B][k2=1 8B],
// bytes = Wfp8[row = t*16 + (l&15)][col = kt*64 + k2*32 + ((l>>4)>>1)*16 + ((l>>4)&1)*8 ..+8].
// Logical row 200 = ones (rowsum trick), rows 201..207 = 0.
__global__ __launch_bounds__(256) void prep_w8(const float* __restrict__ W,
                                               unsigned long long* __restrict__ Wq) {
    const int i  = blockIdx.x * 256 + threadIdx.x;   // 12*13*64*2 = 19968 8-byte halves
    const int h  = i & 1;                            // k2
    const int j  = i >> 1;                           // (kt*13+t)*64 + l
    const int l  = j & 63;
    const int r2 = j >> 6;                           // kt*13 + t
    const int t  = r2 % 13;
    const int kt = r2 / 13;
    const int q  = l >> 4, m = l & 15;
    const int row = t * 16 + m;
    const int col = kt * 64 + h * 32 + ((q >> 1) << 4) + ((q & 1) << 3);
    unsigned long long v = 0ull;
    if (row < Csz) {
        const float4 a = *(const float4*)(W + (size_t)row * Dsz + col);
        const float4 b = *(const float4*)(W + (size_t)row * Dsz + col + 4);
        unsigned int lo = __builtin_amdgcn_cvt_pk_fp8_f32(a.x, a.y, 0u, false);
        lo = __builtin_amdgcn_cvt_pk_fp8_f32(a.z, a.w, lo, true);
        unsigned int hi = __builtin_amdgcn_cvt_pk_fp8_f32(b.x, b.y, 0u, false);
        hi = __builtin_amdgcn_cvt_pk_fp8_f32(b.z, b.w, hi, true);
        v = ((unsigned long long)hi << 32) | (unsigned long long)lo;
    } else if (row == Csz) {
        v = 0x3838383838383838ull;   // fp8 e4m3 1.0 x8
    }
    Wq[i] = v;
}

// global classifier runs FIRST: out[b,c] = ct[b]·gw[c] + gb[c]  (exact fp32)
__global__ __launch_bounds__(256) void gc_kernel(
    const float* __restrict__ ct, const float* __restrict__ gw,
    const float* __restrict__ gb, float* __restrict__ out) {
    const int b    = blockIdx.x;
    const int wv   = threadIdx.x >> 6;
    const int lane = threadIdx.x & 63;
    const int c    = blockIdx.y * 4 + wv;
    const float* wr = gw + (size_t)c * Dsz + lane * 12;
    const float* cr = ct + (size_t)b * Dsz + lane * 12;
    float s = 0.f;
#pragma unroll
    for (int j = 0; j < 3; ++j) {
        const float4 w = *(const float4*)(wr + 4 * j);
        const float4 x = *(const float4*)(cr + 4 * j);
        s += w.x * x.x + w.y * x.y + w.z * x.z + w.w * x.w;
    }
#pragma unroll
    for (int off = 32; off > 0; off >>= 1) s += __shfl_down(s, off, 64);
    if (lane == 0) out[b * Csz + c] = s + gb[c];
}

__device__ __forceinline__ long cvtA(const f32x4 lo, const f32x4 hi) {
    union { long l; unsigned int u[2]; } A;
    A.u[0] = __builtin_amdgcn_cvt_pk_fp8_f32(lo.x, lo.y, 0u, false);
    A.u[0] = __builtin_amdgcn_cvt_pk_fp8_f32(lo.z, lo.w, A.u[0], true);
    A.u[1] = __builtin_amdgcn_cvt_pk_fp8_f32(hi.x, hi.y, 0u, false);
    A.u[1] = __builtin_amdgcn_cvt_pk_fp8_f32(hi.z, hi.w, A.u[1], true);
    return A.l;
}

// Split-K restructure: block = 16 rows, 4 waves x K=192 each. Each lane loads
// its ENTIRE X footprint up front (12 dwordx4 -> 768 B CONTIGUOUS per row per
// wave; block collectively = 16 rows x 3 KB fully contiguous, all in flight)
// -> fixes the 256B-granule strided X pattern that capped supply at ~1.6 TB/s.
// W from pre-swizzled global fragments (L1/L2-hot). No main-loop barriers.
// Partial accs merge via 27 KB LDS tree; wave 0 runs the proven epilogue.
__global__ __launch_bounds__(256, 4) void attn_kernel(
    const float* __restrict__ X,            // (B*S, D) fp32
    const unsigned char* __restrict__ Wq,   // swizzled fragments, 156 KB
    const float* __restrict__ attn_b,       // (C,)
    const float* __restrict__ lam,          // (1,)
    float* __restrict__ out)                // (B, C): gscore already written
{
    __shared__ float sred[2][64][53];       // 27136 B (53 = pad)

    const int tid  = threadIdx.x;
    const int lane = tid & 63;
    const int w    = tid >> 6;      // K-half owner: kt = 3w + {0,1,2}
    const int m    = lane & 15;
    const int q    = lane >> 4;
    const int row0 = blockIdx.x * 16;
    const int bidx = blockIdx.x / 36;       // 36 blocks per batch, never crosses

    // A-fragment source: lane (q,m) owns row row0+m, cols w*192 + kt'*64 + k2*32 + q*8
    const float* xp = X + (size_t)(row0 + m) * Dsz + w * 192 + q * 8;
    // B-fragment source: per-lane 16 B within each 1024-B record
    const unsigned char* wp = Wq + lane * 16;

    // ---- load ALL X for this wave now: 12 x dwordx4, 768 B contiguous per row
    f32x4 xr[12];
#pragma unroll
    for (int kk = 0; kk < 3; ++kk) {
#pragma unroll
        for (int j = 0; j < 4; ++j)
            xr[kk * 4 + j] = *(const f32x4*)(xp + kk * 64 + (j >> 1) * 32 + (j & 1) * 4);
    }

    f32x4 acc[13];
#pragma unroll
    for (int t = 0; t < 13; ++t) acc[t] = (f32x4){0.f, 0.f, 0.f, 0.f};

    // ---- 3 K-tile bodies, W records loaded 7+6 to cap live VGPRs
#pragma unroll
    for (int kk = 0; kk < 3; ++kk) {
        const int kt = 3 * w + kk;          // wave-uniform
        const long A0 = cvtA(xr[kk * 4 + 0], xr[kk * 4 + 1]);
        const long A1 = cvtA(xr[kk * 4 + 2], xr[kk * 4 + 3]);
        lx2 wfa[7];
#pragma unroll
        for (int t = 0; t < 7; ++t)
            wfa[t] = *(const lx2*)(wp + (size_t)(kt * 13 + t) * 1024);
        __builtin_amdgcn_s_setprio(1);
#pragma unroll
        for (int t = 0; t < 7; ++t) {
            acc[t] = __builtin_amdgcn_mfma_f32_16x16x32_fp8_fp8(A0, wfa[t][0], acc[t], 0, 0, 0);
            acc[t] = __builtin_amdgcn_mfma_f32_16x16x32_fp8_fp8(A1, wfa[t][1], acc[t], 0, 0, 0);
        }
        __builtin_amdgcn_s_setprio(0);
        lx2 wfb[6];
#pragma unroll
        for (int t = 0; t < 6; ++t)
            wfb[t] = *(const lx2*)(wp + (size_t)(kt * 13 + 7 + t) * 1024);
        __builtin_amdgcn_s_setprio(1);
#pragma unroll
        for (int t = 0; t < 6; ++t) {
            acc[7 + t] = __builtin_amdgcn_mfma_f32_16x16x32_fp8_fp8(A0, wfb[t][0], acc[7 + t], 0, 0, 0);
            acc[7 + t] = __builtin_amdgcn_mfma_f32_16x16x32_fp8_fp8(A1, wfb[t][1], acc[7 + t], 0, 0, 0);
        }
        __builtin_amdgcn_s_setprio(0);
    }

    // ---- split-K merge: waves 2,3 -> LDS; 0,1 add; wave1 -> LDS; wave0 adds
    if (w >= 2) {
#pragma unroll
        for (int t = 0; t < 13; ++t) {
#pragma unroll
            for (int r = 0; r < 4; ++r) sred[w - 2][lane][t * 4 + r] = acc[t][r];
        }
    }
    __syncthreads();
    if (w < 2) {
#pragma unroll
        for (int t = 0; t < 13; ++t) {
#pragma unroll
            for (int r = 0; r < 4; ++r) acc[t][r] += sred[w][lane][t * 4 + r];
        }
    }
    __syncthreads();
    if (w == 1) {
#pragma unroll
        for (int t = 0; t < 13; ++t) {
#pragma unroll
            for (int r = 0; r < 4; ++r) sred[0][lane][t * 4 + r] = acc[t][r];
        }
    }
    __syncthreads();

    if (w == 0) {
#pragma unroll
        for (int t = 0; t < 13; ++t) {
#pragma unroll
            for (int r = 0; r < 4; ++r) acc[t][r] += sred[0][lane][t * 4 + r];
        }
        // rowsum via ones-column: tile 12, col 200 => m==8 lanes; row = q*4+r
        float rsv[4];
#pragma unroll
        for (int r = 0; r < 4; ++r) rsv[r] = __shfl(acc[12][r], (lane & 48) + 8, 64);

        const float scale = lam[0] * (1.f / ((float)Ssz * (float)Dsz));
        // epilogue: C/D col = lane&15, row = q*4+reg; reduce 16 rows, atomic add
#pragma unroll
        for (int t = 0; t < 13; ++t) {
            const int c = t * 16 + m;
            if (c < Csz) {
                const float bias = attn_b[c];
                float s = 0.f;
#pragma unroll
                for (int r = 0; r < 4; ++r)
                    s += rsv[r] / (1.f + __expf(-(acc[t][r] + bias)));
                s += __shfl_xor(s, 16, 64);
                s += __shfl_xor(s, 32, 64);
                if (q == 0) atomicAdd(&out[bidx * Csz + c], s * scale);
            }
        }
    }
}

extern "C" void kernel_launch(void* const* d_in, const int* in_sizes, int n_in,
                              void* d_out, int out_size, void* d_ws, size_t ws_size,
                              hipStream_t stream) {
    const float* X   = (const float*)d_in[0];
    const float* ct  = (const float*)d_in[1];
    const float* aw  = (const float*)d_in[2];
    const float* ab  = (const float*)d_in[3];
    const float* gw  = (const float*)d_in[4];
    const float* gb  = (const float*)d_in[5];
    const float* lam = (const float*)d_in[6];
    float* out = (float*)d_out;
    unsigned long long* Wq = (unsigned long long*)d_ws;   // 12*13*1024 = 156 KB swizzled fp8

    prep_w8<<<(NKT * 13 * 64 * 2) / 256, 256, 0, stream>>>(aw, Wq);
    gc_kernel<<<dim3(Bsz, Csz / 4), 256, 0, stream>>>(ct, gw, gb, out);
    attn_kernel<<<(Bsz * Ssz) / 16, 256, 0, stream>>>(X, (const unsigned char*)Wq, ab, lam, out);
}

// Round 6
// 193.039 us; speedup vs baseline: 1.0820x; 1.0204x over previous
//
#include <hip/hip_runtime.h>
#include <math.h>

// (B,S,D,C) = (64, 576, 768, 200)
#define Bsz  64
#define Ssz  576
#define Dsz  768
#define Csz  200
#define MTL  144        // rows per block; grid 256 = exactly 1 block/CU
#define NKT  12         // K tiles of 64 floats

typedef float f32x4 __attribute__((ext_vector_type(4)));
typedef long  lx2   __attribute__((ext_vector_type(2)));

#define AS_GLOBAL __attribute__((address_space(1)))
#define AS_LDS    __attribute__((address_space(3)))

// async 16B-per-lane global -> LDS (dest = wave-uniform base + lane*16)
__device__ inline void gload16(const void* g, void* l) {
    __builtin_amdgcn_global_load_lds((const AS_GLOBAL unsigned int*)g,
                                     (AS_LDS unsigned int*)l, 16, 0, 0);
}

// one-time: W (200x768 fp32) -> fp8 e4m3 pre-swizzled into MFMA B-fragment order.
// Record (kt,t) = 1024 B at ((kt*13+t)*1024): lane l holds 16 B = [k2=0 8B][k2=1 8B],
// bytes = Wfp8[row = t*16 + (l&15)][col = kt*64 + k2*32 + ((l>>4)>>1)*16 + ((l>>4)&1)*8 ..+8].
// Logical row 200 = ones (rowsum trick), rows 201..207 = 0.
__global__ __launch_bounds__(256) void prep_w8(const float* __restrict__ W,
                                               unsigned long long* __restrict__ Wq) {
    const int i  = blockIdx.x * 256 + threadIdx.x;   // 12*13*64*2 = 19968 8-byte halves
    const int h  = i & 1;                            // k2
    const int j  = i >> 1;                           // (kt*13+t)*64 + l
    const int l  = j & 63;
    const int r2 = j >> 6;                           // kt*13 + t
    const int t  = r2 % 13;
    const int kt = r2 / 13;
    const int q  = l >> 4, m = l & 15;
    const int row = t * 16 + m;
    const int col = kt * 64 + h * 32 + ((q >> 1) << 4) + ((q & 1) << 3);
    unsigned long long v = 0ull;
    if (row < Csz) {
        const float4 a = *(const float4*)(W + (size_t)row * Dsz + col);
        const float4 b = *(const float4*)(W + (size_t)row * Dsz + col + 4);
        unsigned int lo = __builtin_amdgcn_cvt_pk_fp8_f32(a.x, a.y, 0u, false);
        lo = __builtin_amdgcn_cvt_pk_fp8_f32(a.z, a.w, lo, true);
        unsigned int hi = __builtin_amdgcn_cvt_pk_fp8_f32(b.x, b.y, 0u, false);
        hi = __builtin_amdgcn_cvt_pk_fp8_f32(b.z, b.w, hi, true);
        v = ((unsigned long long)hi << 32) | (unsigned long long)lo;
    } else if (row == Csz) {
        v = 0x3838383838383838ull;   // fp8 e4m3 1.0 x8
    }
    Wq[i] = v;
}

// global classifier runs FIRST: out[b,c] = ct[b]·gw[c] + gb[c]  (exact fp32)
__global__ __launch_bounds__(256) void gc_kernel(
    const float* __restrict__ ct, const float* __restrict__ gw,
    const float* __restrict__ gb, float* __restrict__ out) {
    const int b    = blockIdx.x;
    const int wv   = threadIdx.x >> 6;
    const int lane = threadIdx.x & 63;
    const int c    = blockIdx.y * 4 + wv;
    const float* wr = gw + (size_t)c * Dsz + lane * 12;
    const float* cr = ct + (size_t)b * Dsz + lane * 12;
    float s = 0.f;
#pragma unroll
    for (int j = 0; j < 3; ++j) {
        const float4 w = *(const float4*)(wr + 4 * j);
        const float4 x = *(const float4*)(cr + 4 * j);
        s += w.x * x.x + w.y * x.y + w.z * x.z + w.w * x.w;
    }
#pragma unroll
    for (int off = 32; off > 0; off >>= 1) s += __shfl_down(s, off, 64);
    if (lane == 0) out[b * Csz + c] = s + gb[c];
}

__device__ __forceinline__ long cvtA(const f32x4 lo, const f32x4 hi) {
    union { long l; unsigned int u[2]; } A;
    A.u[0] = __builtin_amdgcn_cvt_pk_fp8_f32(lo.x, lo.y, 0u, false);
    A.u[0] = __builtin_amdgcn_cvt_pk_fp8_f32(lo.z, lo.w, A.u[0], true);
    A.u[1] = __builtin_amdgcn_cvt_pk_fp8_f32(hi.x, hi.y, 0u, false);
    A.u[1] = __builtin_amdgcn_cvt_pk_fp8_f32(hi.z, hi.w, A.u[1], true);
    return A.l;
}

// asm-pinned X loads: compiler CANNOT sink/serialize these. Immediate offsets
// (KT*256 + {0,16,128,144} bytes, max 2960 < 4096) off a single base pointer.
#define XLOAD(g, KT) do {                                                        \
    asm volatile("global_load_dwordx4 %0, %1, off offset:%2"                     \
                 : "=v"(g[0]) : "v"(xp), "i"((KT) * 256 + 0));                   \
    asm volatile("global_load_dwordx4 %0, %1, off offset:%2"                     \
                 : "=v"(g[1]) : "v"(xp), "i"((KT) * 256 + 16));                  \
    asm volatile("global_load_dwordx4 %0, %1, off offset:%2"                     \
                 : "=v"(g[2]) : "v"(xp), "i"((KT) * 256 + 128));                 \
    asm volatile("global_load_dwordx4 %0, %1, off offset:%2"                     \
                 : "=v"(g[3]) : "v"(xp), "i"((KT) * 256 + 144));                 \
} while (0)

// One K-tile: counted wait (group KT landed, 3 newer groups stay in flight),
// cvt A, refill the just-consumed group with tile KT+4, then 13 ds_read_b128
// + 26 MFMA from the CU-resident W records.
template<int KT>
__device__ __forceinline__ void body(f32x4 (&g)[4], const float* xp,
                                     const unsigned char* swp, f32x4 (&acc)[13]) {
    constexpr int NWAIT = (KT + 4 < NKT) ? 12 : 4 * (NKT - 1 - KT);
    asm volatile("s_waitcnt vmcnt(%0)" :: "i"(NWAIT) : "memory");
    __builtin_amdgcn_sched_barrier(0);
    const long A0 = cvtA(g[0], g[1]);
    const long A1 = cvtA(g[2], g[3]);
    if constexpr (KT + 4 < NKT) {
        XLOAD(g, KT + 4);
    }
#pragma unroll
    for (int t = 0; t < 13; ++t) {
        const lx2 wf = *(const lx2*)(swp + (KT * 13 + t) * 1024);
        acc[t] = __builtin_amdgcn_mfma_f32_16x16x32_fp8_fp8(A0, wf[0], acc[t], 0, 0, 0);
        acc[t] = __builtin_amdgcn_mfma_f32_16x16x32_fp8_fp8(A1, wf[1], acc[t], 0, 0, 0);
    }
}

// 1 block/CU (grid 256, 576 thr = 9 waves x 16 rows = 144 rows). W staged to
// LDS ONCE per CU (156 KB, linear records, conflict-free reads). X streamed
// via asm-pinned 4-deep per-lane pipeline. One barrier total; counted vmcnt
// only (never 0 mid-loop). Per-CU VMEM: X 432 KB + W 156 KB.
__global__ __launch_bounds__(576, 2) void attn_kernel(
    const float* __restrict__ X,            // (B*S, D) fp32
    const unsigned char* __restrict__ Wq,   // swizzled fragment records, 156 KB
    const float* __restrict__ attn_b,       // (C,)
    const float* __restrict__ lam,          // (1,)
    float* __restrict__ out)                // (B, C): gscore already written
{
    __shared__ unsigned char sW[156 * 1024];   // 12*13 records x 1 KB

    const int tid  = threadIdx.x;
    const int lane = tid & 63;
    const int w    = tid >> 6;      // 0..8, each owns 16 rows x full K
    const int m    = lane & 15;
    const int q    = lane >> 4;
    const int rowbase = blockIdx.x * MTL;
    const int bidx    = blockIdx.x >> 2;       // 4 blocks per batch, never crosses

    // A-fragment source: lane (q,m) of wave w owns row rowbase + w*16 + m,
    // k-floats kt*64 + k2*32 + q*8 .. +8  (verified layout, R2/R5)
    const float* xp = X + (size_t)(rowbase + w * 16 + m) * Dsz + q * 8;
    const unsigned char* swp = sW + lane * 16;

    // ---- W stage FIRST (so the pre-barrier wait drains only W): 156 records,
    // wave w takes 18 (wave 8: 12). Linear src/dst (record format == fragment).
#pragma unroll
    for (int j = 0; j < 18; ++j) {
        const int g = w * 18 + j;
        if (g < 156) gload16(Wq + (size_t)g * 1024 + lane * 16, sW + g * 1024);
    }

    // ---- X groups 0..3 issued now: 16 loads in flight per wave
    f32x4 xg0[4], xg1[4], xg2[4], xg3[4];
    XLOAD(xg0, 0);
    XLOAD(xg1, 1);
    XLOAD(xg2, 2);
    XLOAD(xg3, 3);

    // drain W (oldest 18; wave 8: oldest 12) but keep all 16 X loads flying
    asm volatile("s_waitcnt vmcnt(16)" ::: "memory");
    __builtin_amdgcn_sched_barrier(0);
    asm volatile("s_barrier" ::: "memory");

    f32x4 acc[13];
#pragma unroll
    for (int t = 0; t < 13; ++t) acc[t] = (f32x4){0.f, 0.f, 0.f, 0.f};

    body<0>(xg0, xp, swp, acc);
    body<1>(xg1, xp, swp, acc);
    body<2>(xg2, xp, swp, acc);
    body<3>(xg3, xp, swp, acc);
    body<4>(xg0, xp, swp, acc);
    body<5>(xg1, xp, swp, acc);
    body<6>(xg2, xp, swp, acc);
    body<7>(xg3, xp, swp, acc);
    body<8>(xg0, xp, swp, acc);
    body<9>(xg1, xp, swp, acc);
    body<10>(xg2, xp, swp, acc);
    body<11>(xg3, xp, swp, acc);

    // rowsum via ones-column: tile 12, col 200 => m==8 lanes; row = q*4+r
    float rsv[4];
#pragma unroll
    for (int r = 0; r < 4; ++r) rsv[r] = __shfl(acc[12][r], (lane & 48) + 8, 64);

    const float scale = lam[0] * (1.f / ((float)Ssz * (float)Dsz));
    // epilogue (per wave, rows complete): C/D col = lane&15, row = q*4+reg;
    // reduce the wave's 16 rows, one atomic per class
#pragma unroll
    for (int t = 0; t < 13; ++t) {
        const int c = t * 16 + m;
        if (c < Csz) {
            const float bias = attn_b[c];
            float s = 0.f;
#pragma unroll
            for (int r = 0; r < 4; ++r)
                s += rsv[r] / (1.f + __expf(-(acc[t][r] + bias)));
            s += __shfl_xor(s, 16, 64);
            s += __shfl_xor(s, 32, 64);
            if (q == 0) atomicAdd(&out[bidx * Csz + c], s * scale);
        }
    }
}

extern "C" void kernel_launch(void* const* d_in, const int* in_sizes, int n_in,
                              void* d_out, int out_size, void* d_ws, size_t ws_size,
                              hipStream_t stream) {
    const float* X   = (const float*)d_in[0];
    const float* ct  = (const float*)d_in[1];
    const float* aw  = (const float*)d_in[2];
    const float* ab  = (const float*)d_in[3];
    const float* gw  = (const float*)d_in[4];
    const float* gb  = (const float*)d_in[5];
    const float* lam = (const float*)d_in[6];
    float* out = (float*)d_out;
    unsigned long long* Wq = (unsigned long long*)d_ws;   // 12*13*1024 = 156 KB swizzled fp8

    prep_w8<<<(NKT * 13 * 64 * 2) / 256, 256, 0, stream>>>(aw, Wq);
    gc_kernel<<<dim3(Bsz, Csz / 4), 256, 0, stream>>>(ct, gw, gb, out);
    attn_kernel<<<(Bsz * Ssz) / MTL, 576, 0, stream>>>(X, (const unsigned char*)Wq, ab, lam, out);
}